// Round 7
// baseline (152.061 us; speedup 1.0000x reference)
//
#include <hip/hip_runtime.h>

typedef short  bf16x8  __attribute__((ext_vector_type(8)));
typedef short  short4v __attribute__((ext_vector_type(4)));
typedef float  f32x4   __attribute__((ext_vector_type(4)));

#define NA   32
#define HID  128
#define TPB  8
#define KSTR 136   // s_k ushort row stride (272B, 16B-aligned)
#define VSTR 40    // s_vT ushort row stride (80B, 16B-aligned)

__device__ __forceinline__ unsigned short f2bf(float f) {
  unsigned int u = __float_as_uint(f);
  return (unsigned short)((u + 0x7FFFu + ((u >> 16) & 1u)) >> 16);  // RNE
}
__device__ __forceinline__ float bf2f(unsigned short s) {
  return __uint_as_float(((unsigned int)s) << 16);
}
// LDS-only barrier: does NOT drain vmcnt -> global prefetch rides across.
__device__ __forceinline__ void barrier_lds() {
  asm volatile("s_waitcnt lgkmcnt(0)" ::: "memory");
  __builtin_amdgcn_s_barrier();
  asm volatile("" ::: "memory");
}

__global__ __launch_bounds__(256, 2) void soft_attn_v7(
    const float* __restrict__ h, const float* __restrict__ msg,
    const float* __restrict__ mask,
    const float* __restrict__ qW, const float* __restrict__ qb,
    const float* __restrict__ kW, const float* __restrict__ kb,
    const float* __restrict__ vW, const float* __restrict__ vb,
    const float* __restrict__ dW, const float* __restrict__ db,
    const float* __restrict__ lnw, const float* __restrict__ lnb,
    float* __restrict__ out)
{
  const int t    = threadIdx.x;
  const int lane = t & 63;
  const int w    = t >> 6;        // wave id; owns cols [32w,32w+32), heads {2w,2w+1}
  const int lm   = lane & 15;
  const int lg   = lane >> 4;
  const int n0   = w * 32;
  const int tok0 = blockIdx.x * TPB;

  // Wave-private except s_msgF (one barrier/token, double-buffered).
  __shared__ __align__(16) short          s_msgF[2][8 * 64 * 8];  // 16 KB
  __shared__ __align__(16) unsigned short s_k[NA * KSTR];         // 8704 B  k[a][o] row-major
  __shared__ __align__(16) unsigned short s_vT[HID * VSTR];       // 10240 B v[o][a] col-major
  __shared__ __align__(16) float          s_qall[TPB * HID];      // 4 KB
  __shared__ __align__(16) unsigned short s_pB[8 * NA];           // 512 B  p bf16 per head
  __shared__ __align__(16) short          s_ctxF[4 * 64 * 8];     // 4 KB ctx A-frags
  __shared__ __align__(16) char           s_un[4096];             // hF then dall
  short* s_hF   = (short*)s_un;
  float* s_dall = (float*)s_un;

  // ---- depth-2 msg prefetch regs: P[d] = token parity d ----
  f32x4 P[2][2][2];
#pragma unroll
  for (int d = 0; d < 2; ++d)
#pragma unroll
    for (int j = 0; j < 2; ++j) {
      const int f = j * 4 + w, mt = f >> 2, ks = f & 3;
      const float* mp = msg + (size_t)(tok0 + d) * (NA * HID) + (mt * 16 + lm) * HID + ks * 32 + lg * 8;
      P[d][j][0] = *(const f32x4*)mp; P[d][j][1] = *(const f32x4*)(mp + 4);
    }
  // ---- mask preload ----
  float m8[TPB];
#pragma unroll
  for (int i = 0; i < TPB; ++i) m8[i] = mask[(size_t)(tok0 + i) * NA + (lane & 31)];

  // ---- prologue: zero ctxF pads, h frags, q projection ----
#pragma unroll
  for (int j = 0; j < 4; ++j) ((unsigned int*)s_ctxF)[t + 256 * j] = 0u;
  {
    bf16x8 sv;
#pragma unroll
    for (int e = 0; e < 8; ++e) sv[e] = 0;
    if (lm < TPB) {
      const float* hp = h + (size_t)(tok0 + lm) * HID + w * 32 + lg * 8;
      const f32x4 x0 = *(const f32x4*)hp;
      const f32x4 x1 = *(const f32x4*)(hp + 4);
#pragma unroll
      for (int e = 0; e < 4; ++e) { sv[e] = (short)f2bf(x0[e]); sv[4 + e] = (short)f2bf(x1[e]); }
    }
    ((bf16x8*)s_hF)[w * 64 + lane] = sv;
  }
  {
    bf16x8 Bq[2][4];
    float qb2[2];
#pragma unroll
    for (int nt = 0; nt < 2; ++nt) {
      const int col = n0 + nt * 16 + lm;
      qb2[nt] = qb[col];
#pragma unroll
      for (int ks = 0; ks < 4; ++ks) {
        bf16x8 bq;
#pragma unroll
        for (int e = 0; e < 8; ++e)
          bq[e] = (short)f2bf(qW[(size_t)(ks * 32 + lg * 8 + e) * HID + col]);
        Bq[nt][ks] = bq;
      }
    }
    __syncthreads();
    f32x4 accq[2];
#pragma unroll
    for (int nt = 0; nt < 2; ++nt) accq[nt] = (f32x4){qb2[nt], qb2[nt], qb2[nt], qb2[nt]};
#pragma unroll
    for (int ks = 0; ks < 4; ++ks) {
      const bf16x8 a = ((const bf16x8*)s_hF)[ks * 64 + lane];
#pragma unroll
      for (int nt = 0; nt < 2; ++nt)
        accq[nt] = __builtin_amdgcn_mfma_f32_16x16x32_bf16(a, Bq[nt][ks], accq[nt], 0, 0, 0);
    }
#pragma unroll
    for (int nt = 0; nt < 2; ++nt)
#pragma unroll
      for (int r = 0; r < 4; ++r) {
        const int row = lg * 4 + r;
        if (row < TPB) s_qall[row * HID + n0 + nt * 16 + lm] = accq[nt][r];
      }
  }

  // ---- persistent weight frags + biases ----
  bf16x8 Bk[2][4], Bv[2][4];
  f32x4 kb4[2];            // k bias along o = n0+nt*16+lg*4+r (swapped-C rows)
  float vb2[2];
#pragma unroll
  for (int nt = 0; nt < 2; ++nt) {
    const int col = n0 + nt * 16 + lm;
    kb4[nt] = *(const f32x4*)(kb + n0 + nt * 16 + lg * 4);
    vb2[nt] = vb[col];
#pragma unroll
    for (int ks = 0; ks < 4; ++ks) {
      bf16x8 bk, bv;
#pragma unroll
      for (int e = 0; e < 8; ++e) {
        const size_t r = (size_t)(ks * 32 + lg * 8 + e) * HID + col;
        bk[e] = (short)f2bf(kW[r]); bv[e] = (short)f2bf(vW[r]);
      }
      Bk[nt][ks] = bk; Bv[nt][ks] = bv;
    }
  }

  // ---- main loop (fully unrolled, 1 barrier/token) ----
#pragma unroll
  for (int it = 0; it < TPB; ++it) {
    const int tok = tok0 + it;
    const int buf = it & 1;

    // stage own frags {w, w+4}
#pragma unroll
    for (int j = 0; j < 2; ++j) {
      const int f = j * 4 + w;
      bf16x8 sv;
#pragma unroll
      for (int e = 0; e < 4; ++e) {
        sv[e]     = (short)f2bf(P[buf][j][0][e]);
        sv[4 + e] = (short)f2bf(P[buf][j][1][e]);
      }
      ((bf16x8*)(&s_msgF[buf][0]))[f * 64 + lane] = sv;
    }
    // re-issue prefetch for it+2 (consumed 2 iters later; rides across barrier)
    if (it + 2 < TPB) {
#pragma unroll
      for (int j = 0; j < 2; ++j) {
        const int f = j * 4 + w, mt = f >> 2, ks = f & 3;
        const float* mp = msg + (size_t)(tok + 2) * (NA * HID) + (mt * 16 + lm) * HID + ks * 32 + lg * 8;
        P[buf][j][0] = *(const f32x4*)mp; P[buf][j][1] = *(const f32x4*)(mp + 4);
      }
    }
    barrier_lds();   // msgF visible (dbuf covers laggards on buf^1)

    // ---- k projection, SWAPPED (A=Bk, B=msg): lane holds k[a=mt*16+lm][o=n0+nt*16+lg*4+r]
    {
      f32x4 ck[2][2];  // [nt][mt]
#pragma unroll
      for (int nt = 0; nt < 2; ++nt)
#pragma unroll
        for (int mt = 0; mt < 2; ++mt) ck[nt][mt] = kb4[nt];
#pragma unroll
      for (int ks = 0; ks < 4; ++ks) {
        const bf16x8 a0 = ((const bf16x8*)(&s_msgF[buf][0]))[ks * 64 + lane];
        const bf16x8 a1 = ((const bf16x8*)(&s_msgF[buf][0]))[(4 + ks) * 64 + lane];
#pragma unroll
        for (int nt = 0; nt < 2; ++nt) {
          ck[nt][0] = __builtin_amdgcn_mfma_f32_16x16x32_bf16(Bk[nt][ks], a0, ck[nt][0], 0, 0, 0);
          ck[nt][1] = __builtin_amdgcn_mfma_f32_16x16x32_bf16(Bk[nt][ks], a1, ck[nt][1], 0, 0, 0);
        }
      }
#pragma unroll
      for (int nt = 0; nt < 2; ++nt)
#pragma unroll
        for (int mt = 0; mt < 2; ++mt) {
          short4v kp;
#pragma unroll
          for (int r = 0; r < 4; ++r) kp[r] = (short)f2bf(ck[nt][mt][r]);
          *(short4v*)&s_k[(mt * 16 + lm) * KSTR + n0 + nt * 16 + lg * 4] = kp;
        }
    }
    // ---- v projection, normal (A=msg, B=Bv): lane holds v[a=mt*16+lg*4+r][o=n0+nt*16+lm]
    {
      f32x4 cv[2][2];  // [mt][nt]
#pragma unroll
      for (int mt = 0; mt < 2; ++mt)
#pragma unroll
        for (int nt = 0; nt < 2; ++nt) cv[mt][nt] = (f32x4){vb2[nt], vb2[nt], vb2[nt], vb2[nt]};
#pragma unroll
      for (int ks = 0; ks < 4; ++ks) {
        const bf16x8 a0 = ((const bf16x8*)(&s_msgF[buf][0]))[ks * 64 + lane];
        const bf16x8 a1 = ((const bf16x8*)(&s_msgF[buf][0]))[(4 + ks) * 64 + lane];
#pragma unroll
        for (int nt = 0; nt < 2; ++nt) {
          cv[0][nt] = __builtin_amdgcn_mfma_f32_16x16x32_bf16(a0, Bv[nt][ks], cv[0][nt], 0, 0, 0);
          cv[1][nt] = __builtin_amdgcn_mfma_f32_16x16x32_bf16(a1, Bv[nt][ks], cv[1][nt], 0, 0, 0);
        }
      }
#pragma unroll
      for (int mt = 0; mt < 2; ++mt)
#pragma unroll
        for (int nt = 0; nt < 2; ++nt) {
          short4v vp;
#pragma unroll
          for (int r = 0; r < 4; ++r) vp[r] = (short)f2bf(fmaxf(cv[mt][nt][r], 0.f));  // relu
          *(short4v*)&s_vT[(n0 + nt * 16 + lm) * VSTR + mt * 16 + lg * 4] = vp;
        }
    }

    // ---- scores + softmax (no max-reduce; bounded scores) ----
    {
      const int hh = lane >> 5, a = lane & 31;
      const int head = 2 * w + hh;
      const f32x4* qr = (const f32x4*)(s_qall + it * HID + head * 16);
      const bf16x8 k0 = *(const bf16x8*)&s_k[a * KSTR + head * 16];
      const bf16x8 k1 = *(const bf16x8*)&s_k[a * KSTR + head * 16 + 8];
      const f32x4 q0 = qr[0], q1 = qr[1], q2 = qr[2], q3 = qr[3];
      float sc = 0.f;
#pragma unroll
      for (int e = 0; e < 4; ++e) {
        sc = fmaf(q0[e], bf2f((unsigned short)k0[e]), sc);
        sc = fmaf(q1[e], bf2f((unsigned short)k0[4 + e]), sc);
        sc = fmaf(q2[e], bf2f((unsigned short)k1[e]), sc);
        sc = fmaf(q3[e], bf2f((unsigned short)k1[4 + e]), sc);
      }
      const float mk = m8[it];
      sc = sc * 0.25f * mk;
      if (sc == 0.0f) sc = -1000000.0f;   // exact reference semantics
      // exp without max-subtraction: |sc_unmasked| << 80; masked -> exp(-80)=1.8e-35,
      // so all-masked sum = 5.8e-34 (no 0/0), p*mk = 0 matches reference.
      const float ex = __expf(fmaxf(sc, -80.f));
      float sm = ex;
#pragma unroll
      for (int off = 16; off; off >>= 1) sm += __shfl_xor(sm, off);
      s_pB[head * NA + a] = f2bf(ex / sm * mk);
    }

    // ---- PV via MFMA: per nt one 16x16x32 (K = a = 32) ----
#pragma unroll
    for (int nt = 0; nt < 2; ++nt) {
      const int head = 2 * w + nt;
      // A: p broadcast (addr indep of lm -> all A-rows identical -> all C rows = ctx)
      const bf16x8 pa = *(const bf16x8*)&s_pB[head * NA + lg * 8];
      // B: v[a][o], a = lg*8+e contiguous in s_vT row o = n0+nt*16+lm
      const bf16x8 vf = *(const bf16x8*)&s_vT[(n0 + nt * 16 + lm) * VSTR + lg * 8];
      const f32x4 pv = __builtin_amdgcn_mfma_f32_16x16x32_bf16(pa, vf, (f32x4){0.f, 0.f, 0.f, 0.f}, 0, 0, 0);
      if (lg == 0) {
        const int o = n0 + nt * 16 + lm;
        ((unsigned short*)s_ctxF)[(((o >> 5) * 64) + ((o >> 3) & 3) * 16 + it) * 8 + (o & 7)] = f2bf(pv[0]);
      }
    }
  }
  __syncthreads();   // ctxF complete (cross-wave for d-proj)

  // ---- batched d projection ----
  {
    bf16x8 Bd[2][4];
    float db2[2];
#pragma unroll
    for (int nt = 0; nt < 2; ++nt) {
      const int col = n0 + nt * 16 + lm;
      db2[nt] = db[col];
#pragma unroll
      for (int ks = 0; ks < 4; ++ks) {
        bf16x8 bd;
#pragma unroll
        for (int e = 0; e < 8; ++e)
          bd[e] = (short)f2bf(dW[(size_t)(ks * 32 + lg * 8 + e) * HID + col]);
        Bd[nt][ks] = bd;
      }
    }
    f32x4 accd[2];
#pragma unroll
    for (int nt = 0; nt < 2; ++nt) accd[nt] = (f32x4){db2[nt], db2[nt], db2[nt], db2[nt]};
#pragma unroll
    for (int ks = 0; ks < 4; ++ks) {
      const bf16x8 a = ((const bf16x8*)s_ctxF)[ks * 64 + lane];
#pragma unroll
      for (int nt = 0; nt < 2; ++nt)
        accd[nt] = __builtin_amdgcn_mfma_f32_16x16x32_bf16(a, Bd[nt][ks], accd[nt], 0, 0, 0);
    }
#pragma unroll
    for (int nt = 0; nt < 2; ++nt)
#pragma unroll
      for (int r = 0; r < 4; ++r) {
        const int row = lg * 4 + r;
        if (row < TPB) s_dall[row * HID + n0 + nt * 16 + lm] = accd[nt][r];
      }
  }
  __syncthreads();

  // ---- residual + layernorm ----
  {
    const int row = t >> 5, seg = t & 31;
    const f32x4 xd = *(const f32x4*)(s_dall + row * HID + seg * 4);
    const f32x4 xh = *(const f32x4*)(h + (size_t)(tok0 + row) * HID + seg * 4);
    float x[4];
    float s1 = 0.f, s2 = 0.f;
#pragma unroll
    for (int e = 0; e < 4; ++e) { x[e] = xd[e] + xh[e]; s1 += x[e]; s2 += x[e] * x[e]; }
#pragma unroll
    for (int off = 16; off; off >>= 1) { s1 += __shfl_xor(s1, off); s2 += __shfl_xor(s2, off); }
    const float u   = s1 * (1.f / 128.f);
    const float var = s2 * (1.f / 128.f) - u * u;
    const float rs  = rsqrtf(var + 1e-12f);
    const f32x4 w4 = *(const f32x4*)(lnw + seg * 4);
    const f32x4 b4 = *(const f32x4*)(lnb + seg * 4);
    f32x4 y;
#pragma unroll
    for (int e = 0; e < 4; ++e) y[e] = w4[e] * ((x[e] - u) * rs) + b4[e];
    *(f32x4*)(out + (size_t)(tok0 + row) * HID + seg * 4) = y;
  }
}

extern "C" void kernel_launch(void* const* d_in, const int* in_sizes, int n_in,
                              void* d_out, int out_size, void* d_ws, size_t ws_size,
                              hipStream_t stream) {
  const float* h    = (const float*)d_in[0];
  const float* msg  = (const float*)d_in[1];
  const float* mask = (const float*)d_in[2];
  const float* qW   = (const float*)d_in[3];
  const float* qb   = (const float*)d_in[4];
  const float* kW   = (const float*)d_in[5];
  const float* kb   = (const float*)d_in[6];
  const float* vW   = (const float*)d_in[7];
  const float* vb   = (const float*)d_in[8];
  const float* dW   = (const float*)d_in[9];
  const float* db   = (const float*)d_in[10];
  const float* lnw  = (const float*)d_in[11];
  const float* lnb  = (const float*)d_in[12];
  float* out = (float*)d_out;

  const int n_tokens = in_sizes[0] / HID;   // 16384
  const int nblocks  = n_tokens / TPB;      // 2048
  soft_attn_v7<<<nblocks, 256, 0, stream>>>(
      h, msg, mask, qW, qb, kW, kb, vW, vb, dW, db, lnw, lnb, out);
}